// Round 2
// baseline (1090.606 us; speedup 1.0000x reference)
//
#include <hip/hip_runtime.h>
#include <hip/hip_bf16.h>

typedef unsigned int u32;
typedef unsigned long long u64;

#define NB 32          // batches
#define NP 131072      // points per batch
#define BPB 32         // blocks per batch
#define TILE 4096      // elements per block tile
#define THREADS 256
#define IPT 16         // items per thread
#define RADIX_BITS 11
#define RADIX 2048
#define PASSES 6

// ---------------- Hilbert encode (Skilling AxesToTranspose + interleave) ----------------

__device__ __forceinline__ u64 spread3(u32 v) {
    u64 x = (u64)(v & 0x1FFFFFu);
    x = (x | (x << 32)) & 0x001F00000000FFFFull;
    x = (x | (x << 16)) & 0x001F0000FF0000FFull;
    x = (x | (x << 8))  & 0x100F00F00F00F00Full;
    x = (x | (x << 4))  & 0x10C30C30C30C30C3ull;
    x = (x | (x << 2))  & 0x1249249249249249ull;
    return x;
}

__device__ __forceinline__ u64 hilbert3d(u32 x0, u32 x1, u32 x2) {
    // num_bits = 21, M = 1<<20
    #pragma unroll
    for (int q = 20; q >= 1; --q) {
        u32 Q = 1u << q, P = Q - 1u;
        // i = 0: t = 0
        if (x0 & Q) x0 ^= P;
        // i = 1
        u32 t = (x0 ^ x1) & P;
        if (x1 & Q) { x0 ^= P; } else { x0 ^= t; x1 ^= t; }
        // i = 2
        t = (x0 ^ x2) & P;
        if (x2 & Q) { x0 ^= P; } else { x0 ^= t; x2 ^= t; }
    }
    // Gray encode
    x1 ^= x0;
    x2 ^= x1;
    u32 t2 = 0;
    #pragma unroll
    for (int q = 20; q >= 1; --q) {
        if (x2 & (1u << q)) t2 ^= (1u << q) - 1u;
    }
    x0 ^= t2; x1 ^= t2; x2 ^= t2;
    // interleave: bit b of x[i] -> position b*3 + (2-i)
    return (spread3(x0) << 2) | (spread3(x1) << 1) | spread3(x2);
}

// ---------------- Stats: centroid ----------------

__global__ __launch_bounds__(THREADS) void k_sum(const float* __restrict__ z,
                                                 double* __restrict__ partial) {
    int b = blockIdx.y, blk = blockIdx.x, tid = threadIdx.x;
    const float* zb = z + ((size_t)b * NP + (size_t)blk * TILE) * 3;
    double s0 = 0.0, s1 = 0.0, s2 = 0.0;
    #pragma unroll
    for (int r = 0; r < IPT; ++r) {
        int p = r * THREADS + tid;
        s0 += (double)zb[p * 3 + 0];
        s1 += (double)zb[p * 3 + 1];
        s2 += (double)zb[p * 3 + 2];
    }
    for (int off = 32; off > 0; off >>= 1) {
        s0 += __shfl_down(s0, off);
        s1 += __shfl_down(s1, off);
        s2 += __shfl_down(s2, off);
    }
    __shared__ double red[4][3];
    int lane = tid & 63, wave = tid >> 6;
    if (lane == 0) { red[wave][0] = s0; red[wave][1] = s1; red[wave][2] = s2; }
    __syncthreads();
    if (tid == 0) {
        size_t o = ((size_t)b * BPB + blk) * 3;
        partial[o + 0] = red[0][0] + red[1][0] + red[2][0] + red[3][0];
        partial[o + 1] = red[0][1] + red[1][1] + red[2][1] + red[3][1];
        partial[o + 2] = red[0][2] + red[1][2] + red[2][2] + red[3][2];
    }
}

__global__ __launch_bounds__(64) void k_centroid(const double* __restrict__ partial,
                                                 double* __restrict__ cent) {
    int b = blockIdx.x, lane = threadIdx.x;
    double v0 = 0.0, v1 = 0.0, v2 = 0.0;
    if (lane < BPB) {
        size_t o = ((size_t)b * BPB + lane) * 3;
        v0 = partial[o + 0]; v1 = partial[o + 1]; v2 = partial[o + 2];
    }
    for (int off = 32; off > 0; off >>= 1) {
        v0 += __shfl_down(v0, off);
        v1 += __shfl_down(v1, off);
        v2 += __shfl_down(v2, off);
    }
    if (lane == 0) {
        cent[b * 4 + 0] = v0 / (double)NP;
        cent[b * 4 + 1] = v1 / (double)NP;
        cent[b * 4 + 2] = v2 / (double)NP;
    }
}

// ---------------- Stats: radius ----------------

__global__ __launch_bounds__(THREADS) void k_maxp(const float* __restrict__ z,
                                                  const double* __restrict__ cent,
                                                  double* __restrict__ pmax) {
    int b = blockIdx.y, blk = blockIdx.x, tid = threadIdx.x;
    double c0 = cent[b * 4 + 0], c1 = cent[b * 4 + 1], c2 = cent[b * 4 + 2];
    const float* zb = z + ((size_t)b * NP + (size_t)blk * TILE) * 3;
    double m = 0.0;
    #pragma unroll
    for (int r = 0; r < IPT; ++r) {
        int p = r * THREADS + tid;
        double d0 = (double)zb[p * 3 + 0] - c0;
        double d1 = (double)zb[p * 3 + 1] - c1;
        double d2 = (double)zb[p * 3 + 2] - c2;
        double s = (d0 * d0 + d1 * d1) + d2 * d2;   // numpy sum order over axis=2
        m = fmax(m, s);
    }
    for (int off = 32; off > 0; off >>= 1) m = fmax(m, __shfl_down(m, off));
    __shared__ double red[4];
    int lane = tid & 63, wave = tid >> 6;
    if (lane == 0) red[wave] = m;
    __syncthreads();
    if (tid == 0) pmax[(size_t)b * BPB + blk] = fmax(fmax(red[0], red[1]), fmax(red[2], red[3]));
}

__global__ __launch_bounds__(64) void k_radius(const double* __restrict__ pmax,
                                               double* __restrict__ rad) {
    int b = blockIdx.x, lane = threadIdx.x;
    double m = (lane < BPB) ? pmax[(size_t)b * BPB + lane] : 0.0;
    for (int off = 32; off > 0; off >>= 1) m = fmax(m, __shfl_down(m, off));
    if (lane == 0) {
        double r = sqrt(m);
        double zr = r + 1e-6;
        rad[b * 2 + 0] = zr;
        rad[b * 2 + 1] = 2.0 * zr;
    }
}

// ---------------- Encode keys + pass-0 histogram ----------------

__global__ __launch_bounds__(THREADS) void k_encode(const float* __restrict__ z,
                                                    const double* __restrict__ cent,
                                                    const double* __restrict__ rad,
                                                    u64* __restrict__ keys,
                                                    u32* __restrict__ idx,
                                                    u32* __restrict__ hist) {
    int b = blockIdx.y, blk = blockIdx.x, tid = threadIdx.x;
    __shared__ u32 lh[RADIX];
    for (int d = tid; d < RADIX; d += THREADS) lh[d] = 0;
    __syncthreads();
    double c0 = cent[b * 4 + 0], c1 = cent[b * 4 + 1], c2 = cent[b * 4 + 2];
    double zr = rad[b * 2 + 0], tz = rad[b * 2 + 1];
    for (int r = 0; r < IPT; ++r) {
        int p = blk * TILE + r * THREADS + tid;
        size_t zi = ((size_t)b * NP + p) * 3;
        double v0 = (((double)z[zi + 0] - c0) + zr) / tz;
        double v1 = (((double)z[zi + 1] - c1) + zr) / tz;
        double v2 = (((double)z[zi + 2] - c2) + zr) / tz;
        u32 g0 = (u32)(1048576.0 * v0) + 32767u;
        u32 g1 = (u32)(1048576.0 * v1) + 32767u;
        u32 g2 = (u32)(1048576.0 * v2) + 32767u;
        u64 h = hilbert3d(g0, g1, g2);
        size_t e = (size_t)b * NP + p;
        keys[e] = h;
        idx[e] = (u32)p;
        atomicAdd(&lh[(u32)h & (RADIX - 1u)], 1u);
    }
    __syncthreads();
    for (int d = tid; d < RADIX; d += THREADS)
        hist[((size_t)b * RADIX + d) * BPB + blk] = lh[d];
}

// ---------------- Per-pass histogram (passes 1..5) ----------------

__global__ __launch_bounds__(THREADS) void k_hist(const u64* __restrict__ keys,
                                                  u32* __restrict__ hist, int shift) {
    int b = blockIdx.y, blk = blockIdx.x, tid = threadIdx.x;
    __shared__ u32 lh[RADIX];
    for (int d = tid; d < RADIX; d += THREADS) lh[d] = 0;
    __syncthreads();
    size_t base = (size_t)b * NP + (size_t)blk * TILE;
    for (int r = 0; r < IPT; ++r) {
        u64 k = keys[base + r * THREADS + tid];
        atomicAdd(&lh[(u32)(k >> shift) & (RADIX - 1u)], 1u);
    }
    __syncthreads();
    for (int d = tid; d < RADIX; d += THREADS)
        hist[((size_t)b * RADIX + d) * BPB + blk] = lh[d];
}

// ---------------- Scan: hist counts -> scatter bases (per batch) ----------------

__global__ __launch_bounds__(THREADS) void k_scan(u32* __restrict__ hist) {
    int b = blockIdx.x, tid = threadIdx.x;
    int lane = tid & 63, wave = tid >> 6;
    u32 s = 0;
    int d0 = tid * (RADIX / THREADS);   // 8 digits per thread
    #pragma unroll
    for (int j = 0; j < RADIX / THREADS; ++j) {
        size_t base = ((size_t)b * RADIX + (d0 + j)) * BPB;
        u32 t = 0;
        for (int k = 0; k < BPB; ++k) t += hist[base + k];
        s += t;
    }
    // exclusive scan of per-thread sums across 256 threads
    u32 v = s;
    for (int off = 1; off < 64; off <<= 1) {
        u32 n = __shfl_up(v, off);
        if (lane >= off) v += n;
    }
    __shared__ u32 wsum[4];
    if (lane == 63) wsum[wave] = v;
    __syncthreads();
    u32 woff = 0;
    for (int w = 0; w < 4; ++w)
        if (w < wave) woff += wsum[w];
    u32 run = woff + v - s;   // exclusive prefix for this thread's first digit
    #pragma unroll
    for (int j = 0; j < RADIX / THREADS; ++j) {
        size_t base = ((size_t)b * RADIX + (d0 + j)) * BPB;
        u32 cur = run;
        for (int k = 0; k < BPB; ++k) {
            u32 old = hist[base + k];
            hist[base + k] = cur;
            cur += old;
        }
        run = cur;
    }
}

// ---------------- Stable scatter ----------------
// Element order within tile is (wave, item, lane): wave w owns contiguous
// [w*1024, (w+1)*1024), item it covers [it*64, it*64+64) lane-ordered.
// Each wave keeps a private LDS counter row -> no cross-wave serialization;
// a single cross-wave prefix fix-up after phase 1 restores global stability.

__global__ __launch_bounds__(THREADS) void k_scatter(const u64* __restrict__ keyIn,
                                                     const u32* __restrict__ idxIn,
                                                     u64* __restrict__ keyOut,
                                                     u32* __restrict__ idxOut,
                                                     const u32* __restrict__ hist,
                                                     int shift, int writeKeys) {
    int b = blockIdx.y, blk = blockIdx.x, tid = threadIdx.x;
    int lane = tid & 63, wave = tid >> 6;
    __shared__ u32 baseS[RADIX];
    __shared__ unsigned short wrun[4 * RADIX];
    for (int d = tid; d < RADIX; d += THREADS)
        baseS[d] = hist[((size_t)b * RADIX + d) * BPB + blk];
    u32* wz = (u32*)wrun;
    for (int i = tid; i < 2 * RADIX; i += THREADS) wz[i] = 0;
    __syncthreads();

    size_t chunk = (size_t)b * NP + (size_t)blk * TILE + (size_t)wave * 1024;
    u64 keys[IPT];
    u32 idxs[IPT];
    u32 dr[IPT];
    u64 lmask = (1ull << lane) - 1ull;

    #pragma unroll
    for (int it = 0; it < IPT; ++it) {
        size_t e = chunk + it * 64 + lane;
        u64 k = keyIn[e];
        u32 ix = idxIn[e];
        u32 d = (u32)(k >> shift) & (RADIX - 1u);
        u64 m = ~0ull;
        #pragma unroll
        for (int bb = 0; bb < RADIX_BITS; ++bb) {
            u64 bal = __ballot((d >> bb) & 1u);
            m &= ((d >> bb) & 1u) ? bal : ~bal;
        }
        u32 lower = (u32)__popcll(m & lmask);
        u32 base = (u32)wrun[wave * RADIX + d];     // same value for all same-digit lanes
        if (lower == 0)                              // unique leader per digit per wave
            wrun[wave * RADIX + d] = (unsigned short)(base + (u32)__popcll(m));
        keys[it] = k;
        idxs[it] = ix;
        dr[it] = (d << 16) | (base + lower);
    }
    __syncthreads();
    // cross-wave exclusive prefix per digit (stored back into wrun)
    for (int d = tid; d < RADIX; d += THREADS) {
        u32 run = 0;
        for (int w = 0; w < 4; ++w) {
            u32 c = wrun[w * RADIX + d];
            wrun[w * RADIX + d] = (unsigned short)run;
            run += c;
        }
    }
    __syncthreads();
    #pragma unroll
    for (int it = 0; it < IPT; ++it) {
        u32 d = dr[it] >> 16;
        u32 r = dr[it] & 0xFFFFu;
        size_t dst = (size_t)b * NP + baseS[d] + (u32)wrun[wave * RADIX + d] + r;
        if (writeKeys) keyOut[dst] = keys[it];
        idxOut[dst] = idxs[it];
    }
}

// ---------------- Final output: idx_pa + inverse (int32 outputs) ----------------

__global__ __launch_bounds__(THREADS) void k_out(const u32* __restrict__ idxS,
                                                 int* __restrict__ out0,
                                                 int* __restrict__ out1) {
    int b = blockIdx.y, blk = blockIdx.x, tid = threadIdx.x;
    for (int r = 0; r < IPT; ++r) {
        int pos = blk * TILE + r * THREADS + tid;
        u32 ix = idxS[(size_t)b * NP + pos];
        out0[(size_t)b * NP + pos] = (int)ix;   // idx_pa
        out1[(size_t)b * NP + ix] = (int)pos;   // idx_re (inverse permutation)
    }
}

// ---------------- Launch ----------------

extern "C" void kernel_launch(void* const* d_in, const int* in_sizes, int n_in,
                              void* d_out, int out_size, void* d_ws, size_t ws_size,
                              hipStream_t stream) {
    const float* z = (const float*)d_in[0];
    int* out0 = (int*)d_out;
    int* out1 = out0 + (size_t)NB * NP;

    char* ws = (char*)d_ws;
    u64* keysA = (u64*)(ws);                          // 33,554,432 B
    u64* keysB = (u64*)(ws + 33554432);               // 33,554,432 B
    u32* idxA  = (u32*)(ws + 67108864);               // 16,777,216 B
    u32* idxB  = (u32*)(ws + 83886080);               // 16,777,216 B
    u32* hist  = (u32*)(ws + 100663296);              //  8,388,608 B
    double* partial = (double*)(ws + 109051904);      //     24,576 B
    double* pmax    = (double*)(ws + 109076480);      //      8,192 B
    double* cent    = (double*)(ws + 109084672);      //      1,024 B
    double* rad     = (double*)(ws + 109085696);      //        512 B

    dim3 grid(BPB, NB);

    k_sum<<<grid, THREADS, 0, stream>>>(z, partial);
    k_centroid<<<NB, 64, 0, stream>>>(partial, cent);
    k_maxp<<<grid, THREADS, 0, stream>>>(z, cent, pmax);
    k_radius<<<NB, 64, 0, stream>>>(pmax, rad);
    k_encode<<<grid, THREADS, 0, stream>>>(z, cent, rad, keysA, idxA, hist);

    u64 *kin = keysA, *kout = keysB;
    u32 *iin = idxA, *iout = idxB;
    for (int p = 0; p < PASSES; ++p) {
        k_scan<<<NB, THREADS, 0, stream>>>(hist);
        k_scatter<<<grid, THREADS, 0, stream>>>(kin, iin, kout, iout, hist,
                                                p * RADIX_BITS, (p < PASSES - 1) ? 1 : 0);
        if (p < PASSES - 1)
            k_hist<<<grid, THREADS, 0, stream>>>(kout, hist, (p + 1) * RADIX_BITS);
        u64* tk = kin; kin = kout; kout = tk;
        u32* ti = iin; iin = iout; iout = ti;
    }
    // After even number of passes data is back in the A buffers (iin == idxA).
    k_out<<<grid, THREADS, 0, stream>>>(iin, out0, out1);
}

// Round 3
// 492.847 us; speedup vs baseline: 2.2129x; 2.2129x over previous
//
#include <hip/hip_runtime.h>
#include <hip/hip_bf16.h>

typedef unsigned int u32;
typedef unsigned long long u64;

#define NB 32          // batches
#define NP 131072      // points per batch
#define BPB 32         // blocks per batch
#define TILE 4096      // elements per block tile
#define THREADS 256
#define IPT 16         // items per thread
#define RADIX_BITS 8
#define RADIX 256
#define PASSES 8       // 8 x 8 = 64 >= 63 key bits

// XCD-aware swizzle: assumes round-robin workgroup->XCD dispatch (id % 8).
// Maps all 32 blocks of batch b onto XCD b/4 so the batch's 1.5 MB sort
// region + 0.5 MB inverse-perm region stay in one XCD's 4 MB L2.
// Performance heuristic only — correctness never depends on placement.
__device__ __forceinline__ void unswizzle(int id, int& b, int& blk) {
    int xcd = id & 7, j = id >> 3;          // j in [0,128)
    b = xcd * 4 + (j >> 5);                 // 4 batches per XCD
    blk = j & 31;
}

// ---------------- Hilbert encode (Skilling AxesToTranspose + interleave) ----------------

__device__ __forceinline__ u64 spread3(u32 v) {
    u64 x = (u64)(v & 0x1FFFFFu);
    x = (x | (x << 32)) & 0x001F00000000FFFFull;
    x = (x | (x << 16)) & 0x001F0000FF0000FFull;
    x = (x | (x << 8))  & 0x100F00F00F00F00Full;
    x = (x | (x << 4))  & 0x10C30C30C30C30C3ull;
    x = (x | (x << 2))  & 0x1249249249249249ull;
    return x;
}

__device__ __forceinline__ u64 hilbert3d(u32 x0, u32 x1, u32 x2) {
    #pragma unroll
    for (int q = 20; q >= 1; --q) {
        u32 Q = 1u << q, P = Q - 1u;
        if (x0 & Q) x0 ^= P;
        u32 t = (x0 ^ x1) & P;
        if (x1 & Q) { x0 ^= P; } else { x0 ^= t; x1 ^= t; }
        t = (x0 ^ x2) & P;
        if (x2 & Q) { x0 ^= P; } else { x0 ^= t; x2 ^= t; }
    }
    x1 ^= x0;
    x2 ^= x1;
    u32 t2 = 0;
    #pragma unroll
    for (int q = 20; q >= 1; --q) {
        if (x2 & (1u << q)) t2 ^= (1u << q) - 1u;
    }
    x0 ^= t2; x1 ^= t2; x2 ^= t2;
    return (spread3(x0) << 2) | (spread3(x1) << 1) | spread3(x2);
}

// ---------------- Stats: centroid ----------------

__global__ __launch_bounds__(THREADS) void k_sum(const float* __restrict__ z,
                                                 double* __restrict__ partial) {
    int b, blk; unswizzle(blockIdx.x, b, blk);
    int tid = threadIdx.x;
    const float* zb = z + ((size_t)b * NP + (size_t)blk * TILE) * 3;
    double s0 = 0.0, s1 = 0.0, s2 = 0.0;
    #pragma unroll
    for (int r = 0; r < IPT; ++r) {
        int p = r * THREADS + tid;
        s0 += (double)zb[p * 3 + 0];
        s1 += (double)zb[p * 3 + 1];
        s2 += (double)zb[p * 3 + 2];
    }
    for (int off = 32; off > 0; off >>= 1) {
        s0 += __shfl_down(s0, off);
        s1 += __shfl_down(s1, off);
        s2 += __shfl_down(s2, off);
    }
    __shared__ double red[4][3];
    int lane = tid & 63, wave = tid >> 6;
    if (lane == 0) { red[wave][0] = s0; red[wave][1] = s1; red[wave][2] = s2; }
    __syncthreads();
    if (tid == 0) {
        size_t o = ((size_t)b * BPB + blk) * 3;
        partial[o + 0] = red[0][0] + red[1][0] + red[2][0] + red[3][0];
        partial[o + 1] = red[0][1] + red[1][1] + red[2][1] + red[3][1];
        partial[o + 2] = red[0][2] + red[1][2] + red[2][2] + red[3][2];
    }
}

__global__ __launch_bounds__(64) void k_centroid(const double* __restrict__ partial,
                                                 double* __restrict__ cent) {
    int b = blockIdx.x, lane = threadIdx.x;
    double v0 = 0.0, v1 = 0.0, v2 = 0.0;
    if (lane < BPB) {
        size_t o = ((size_t)b * BPB + lane) * 3;
        v0 = partial[o + 0]; v1 = partial[o + 1]; v2 = partial[o + 2];
    }
    for (int off = 32; off > 0; off >>= 1) {
        v0 += __shfl_down(v0, off);
        v1 += __shfl_down(v1, off);
        v2 += __shfl_down(v2, off);
    }
    if (lane == 0) {
        cent[b * 4 + 0] = v0 / (double)NP;
        cent[b * 4 + 1] = v1 / (double)NP;
        cent[b * 4 + 2] = v2 / (double)NP;
    }
}

// ---------------- Stats: radius ----------------

__global__ __launch_bounds__(THREADS) void k_maxp(const float* __restrict__ z,
                                                  const double* __restrict__ cent,
                                                  double* __restrict__ pmax) {
    int b, blk; unswizzle(blockIdx.x, b, blk);
    int tid = threadIdx.x;
    double c0 = cent[b * 4 + 0], c1 = cent[b * 4 + 1], c2 = cent[b * 4 + 2];
    const float* zb = z + ((size_t)b * NP + (size_t)blk * TILE) * 3;
    double m = 0.0;
    #pragma unroll
    for (int r = 0; r < IPT; ++r) {
        int p = r * THREADS + tid;
        double d0 = (double)zb[p * 3 + 0] - c0;
        double d1 = (double)zb[p * 3 + 1] - c1;
        double d2 = (double)zb[p * 3 + 2] - c2;
        double s = (d0 * d0 + d1 * d1) + d2 * d2;
        m = fmax(m, s);
    }
    for (int off = 32; off > 0; off >>= 1) m = fmax(m, __shfl_down(m, off));
    __shared__ double red[4];
    int lane = tid & 63, wave = tid >> 6;
    if (lane == 0) red[wave] = m;
    __syncthreads();
    if (tid == 0) pmax[(size_t)b * BPB + blk] = fmax(fmax(red[0], red[1]), fmax(red[2], red[3]));
}

__global__ __launch_bounds__(64) void k_radius(const double* __restrict__ pmax,
                                               double* __restrict__ rad) {
    int b = blockIdx.x, lane = threadIdx.x;
    double m = (lane < BPB) ? pmax[(size_t)b * BPB + lane] : 0.0;
    for (int off = 32; off > 0; off >>= 1) m = fmax(m, __shfl_down(m, off));
    if (lane == 0) {
        double r = sqrt(m);
        double zr = r + 1e-6;
        rad[b * 2 + 0] = zr;
        rad[b * 2 + 1] = 2.0 * zr;
    }
}

// ---------------- Encode keys + pass-0 histogram ----------------

__global__ __launch_bounds__(THREADS) void k_encode(const float* __restrict__ z,
                                                    const double* __restrict__ cent,
                                                    const double* __restrict__ rad,
                                                    u64* __restrict__ keys,
                                                    u32* __restrict__ idx,
                                                    u32* __restrict__ hist) {
    int b, blk; unswizzle(blockIdx.x, b, blk);
    int tid = threadIdx.x;
    __shared__ u32 lh[RADIX];
    lh[tid] = 0;
    __syncthreads();
    double c0 = cent[b * 4 + 0], c1 = cent[b * 4 + 1], c2 = cent[b * 4 + 2];
    double zr = rad[b * 2 + 0], tz = rad[b * 2 + 1];
    for (int r = 0; r < IPT; ++r) {
        int p = blk * TILE + r * THREADS + tid;
        size_t zi = ((size_t)b * NP + p) * 3;
        double v0 = (((double)z[zi + 0] - c0) + zr) / tz;
        double v1 = (((double)z[zi + 1] - c1) + zr) / tz;
        double v2 = (((double)z[zi + 2] - c2) + zr) / tz;
        u32 g0 = (u32)(1048576.0 * v0) + 32767u;
        u32 g1 = (u32)(1048576.0 * v1) + 32767u;
        u32 g2 = (u32)(1048576.0 * v2) + 32767u;
        u64 h = hilbert3d(g0, g1, g2);
        size_t e = (size_t)b * NP + p;
        keys[e] = h;
        idx[e] = (u32)p;
        atomicAdd(&lh[(u32)h & (RADIX - 1u)], 1u);
    }
    __syncthreads();
    hist[((size_t)b * RADIX + tid) * BPB + blk] = lh[tid];
}

// ---------------- Per-pass histogram (passes 1..7) ----------------

__global__ __launch_bounds__(THREADS) void k_hist(const u64* __restrict__ keys,
                                                  u32* __restrict__ hist, int shift) {
    int b, blk; unswizzle(blockIdx.x, b, blk);
    int tid = threadIdx.x;
    __shared__ u32 lh[RADIX];
    lh[tid] = 0;
    __syncthreads();
    size_t base = (size_t)b * NP + (size_t)blk * TILE;
    for (int r = 0; r < IPT; ++r) {
        u64 k = keys[base + r * THREADS + tid];
        atomicAdd(&lh[(u32)(k >> shift) & (RADIX - 1u)], 1u);
    }
    __syncthreads();
    hist[((size_t)b * RADIX + tid) * BPB + blk] = lh[tid];
}

// ---------------- Scan: hist counts -> scatter bases (per batch) ----------------

__global__ __launch_bounds__(THREADS) void k_scan(u32* __restrict__ hist) {
    int id = blockIdx.x;
    int b = (id & 7) * 4 + (id >> 3);       // batch b processed on XCD b/4
    int tid = threadIdx.x, lane = tid & 63, wave = tid >> 6;
    size_t base = ((size_t)b * RADIX + tid) * BPB;
    u32 c[BPB];
    u32 s = 0;
    #pragma unroll
    for (int k = 0; k < BPB; ++k) { c[k] = hist[base + k]; s += c[k]; }
    u32 v = s;
    for (int off = 1; off < 64; off <<= 1) {
        u32 n = __shfl_up(v, off);
        if (lane >= off) v += n;
    }
    __shared__ u32 wsum[4];
    if (lane == 63) wsum[wave] = v;
    __syncthreads();
    u32 woff = 0;
    for (int w = 0; w < 4; ++w)
        if (w < wave) woff += wsum[w];
    u32 run = woff + v - s;
    #pragma unroll
    for (int k = 0; k < BPB; ++k) { hist[base + k] = run; run += c[k]; }
}

// ---------------- Stable LDS-staged scatter ----------------
// Phase 1: each wave ranks its elements (ballot digit-match) with private
//   per-wave counters (element order = (wave, item, lane) = memory order).
// Phase 2: cross-wave prefix per digit + block-wide exclusive scan over
//   digit counts -> block-local digit starts.
// Phase 3: stage (key, idx) into LDS in digit-sorted order.
// Phase 4: write out in ascending slot order -> global stores form
//   contiguous per-digit runs (avg TILE/RADIX = 16 elems = 192 B).
// Final pass writes idx_pa / idx_re directly instead of key/idx.

__global__ __launch_bounds__(THREADS) void k_scatter(const u64* __restrict__ keyIn,
                                                     const u32* __restrict__ idxIn,
                                                     u64* __restrict__ keyOut,
                                                     u32* __restrict__ idxOut,
                                                     const u32* __restrict__ hist,
                                                     int shift, int lastPass,
                                                     int* __restrict__ out0,
                                                     int* __restrict__ out1) {
    int b, blk; unswizzle(blockIdx.x, b, blk);
    int tid = threadIdx.x, lane = tid & 63, wave = tid >> 6;

    __shared__ u32 baseS[RADIX];                   // 1 KB   global bases (d, blk)
    __shared__ unsigned short wrun[4][RADIX];      // 2 KB   per-wave digit counters
    __shared__ unsigned short lstart[RADIX];       // 0.5 KB block-local digit starts
    __shared__ u64 keyS[TILE];                     // 32 KB  staged keys
    __shared__ u32 idxS[TILE];                     // 16 KB  staged payloads
    __shared__ u32 wsum[4];

    baseS[tid] = hist[((size_t)b * RADIX + tid) * BPB + blk];
    wrun[0][tid] = 0; wrun[1][tid] = 0; wrun[2][tid] = 0; wrun[3][tid] = 0;
    __syncthreads();

    size_t chunk = (size_t)b * NP + (size_t)blk * TILE + (size_t)wave * 1024;
    u64 keys[IPT];
    u32 idxs[IPT];
    u32 dr[IPT];
    u64 lmask = (1ull << lane) - 1ull;

    #pragma unroll
    for (int it = 0; it < IPT; ++it) {
        size_t e = chunk + it * 64 + lane;
        u64 k = keyIn[e];
        u32 ix = idxIn[e];
        u32 d = (u32)(k >> shift) & (RADIX - 1u);
        u64 m = ~0ull;
        #pragma unroll
        for (int bb = 0; bb < RADIX_BITS; ++bb) {
            u64 bal = __ballot((d >> bb) & 1u);
            m &= ((d >> bb) & 1u) ? bal : ~bal;
        }
        u32 lower = (u32)__popcll(m & lmask);
        u32 base = (u32)wrun[wave][d];              // uniform across same-digit lanes
        if (lower == 0)                              // unique leader per digit per wave
            wrun[wave][d] = (unsigned short)(base + (u32)__popcll(m));
        keys[it] = k;
        idxs[it] = ix;
        dr[it] = (d << 16) | (base + lower);
    }
    __syncthreads();

    // cross-wave exclusive prefix per digit; block digit count -> lstart
    {
        u32 run = 0;
        #pragma unroll
        for (int w = 0; w < 4; ++w) {
            u32 c = wrun[w][tid];
            wrun[w][tid] = (unsigned short)run;
            run += c;
        }
        lstart[tid] = (unsigned short)run;
    }
    __syncthreads();

    // block-wide exclusive scan over the 256 digit counts
    {
        u32 cnt = lstart[tid];
        u32 v = cnt;
        for (int off = 1; off < 64; off <<= 1) {
            u32 n = __shfl_up(v, off);
            if (lane >= off) v += n;
        }
        if (lane == 63) wsum[wave] = v;
        __syncthreads();
        u32 woff = 0;
        for (int w = 0; w < 4; ++w)
            if (w < wave) woff += wsum[w];
        lstart[tid] = (unsigned short)(woff + v - cnt);
    }
    __syncthreads();

    // stage into digit-sorted LDS order
    #pragma unroll
    for (int it = 0; it < IPT; ++it) {
        u32 d = dr[it] >> 16;
        u32 r = dr[it] & 0xFFFFu;
        u32 slot = (u32)lstart[d] + (u32)wrun[wave][d] + r;
        keyS[slot] = keys[it];
        idxS[slot] = idxs[it];
    }
    __syncthreads();

    // coalesced write-out (ascending destinations, per-digit runs)
    if (!lastPass) {
        #pragma unroll
        for (int r = 0; r < IPT; ++r) {
            int s = r * THREADS + tid;
            u64 k = keyS[s];
            u32 d = (u32)(k >> shift) & (RADIX - 1u);
            u32 pos = baseS[d] + (u32)s - (u32)lstart[d];
            size_t dst = (size_t)b * NP + pos;
            keyOut[dst] = k;
            idxOut[dst] = idxS[s];
        }
    } else {
        #pragma unroll
        for (int r = 0; r < IPT; ++r) {
            int s = r * THREADS + tid;
            u64 k = keyS[s];
            u32 d = (u32)(k >> shift) & (RADIX - 1u);
            u32 pos = baseS[d] + (u32)s - (u32)lstart[d];
            u32 ix = idxS[s];
            out0[(size_t)b * NP + pos] = (int)ix;   // idx_pa
            out1[(size_t)b * NP + ix] = (int)pos;   // idx_re (L2-local via XCD swizzle)
        }
    }
}

// ---------------- Launch ----------------

extern "C" void kernel_launch(void* const* d_in, const int* in_sizes, int n_in,
                              void* d_out, int out_size, void* d_ws, size_t ws_size,
                              hipStream_t stream) {
    const float* z = (const float*)d_in[0];
    int* out0 = (int*)d_out;
    int* out1 = out0 + (size_t)NB * NP;

    char* ws = (char*)d_ws;
    u64* keysA = (u64*)(ws);                          // 33,554,432 B
    u64* keysB = (u64*)(ws + 33554432);               // 33,554,432 B
    u32* idxA  = (u32*)(ws + 67108864);               // 16,777,216 B
    u32* idxB  = (u32*)(ws + 83886080);               // 16,777,216 B
    u32* hist  = (u32*)(ws + 100663296);              //  1,048,576 B (32*256*32*4)
    double* partial = (double*)(ws + 101711872);      //     24,576 B
    double* pmax    = (double*)(ws + 101736448);      //      8,192 B
    double* cent    = (double*)(ws + 101744640);      //      1,024 B
    double* rad     = (double*)(ws + 101745664);      //        512 B

    const int grid = NB * BPB;   // 1024

    k_sum<<<grid, THREADS, 0, stream>>>(z, partial);
    k_centroid<<<NB, 64, 0, stream>>>(partial, cent);
    k_maxp<<<grid, THREADS, 0, stream>>>(z, cent, pmax);
    k_radius<<<NB, 64, 0, stream>>>(pmax, rad);
    k_encode<<<grid, THREADS, 0, stream>>>(z, cent, rad, keysA, idxA, hist);

    u64 *kin = keysA, *kout = keysB;
    u32 *iin = idxA, *iout = idxB;
    for (int p = 0; p < PASSES; ++p) {
        k_scan<<<NB, THREADS, 0, stream>>>(hist);
        k_scatter<<<grid, THREADS, 0, stream>>>(kin, iin, kout, iout, hist,
                                                p * RADIX_BITS, (p == PASSES - 1) ? 1 : 0,
                                                out0, out1);
        if (p < PASSES - 1)
            k_hist<<<grid, THREADS, 0, stream>>>(kout, hist, (p + 1) * RADIX_BITS);
        u64* tk = kin; kin = kout; kout = tk;
        u32* ti = iin; iin = iout; iout = ti;
    }
}